// Round 4
// baseline (288.998 us; speedup 1.0000x reference)
//
#include <hip/hip_runtime.h>

// ---------- types & helpers ----------
typedef unsigned short u16;
typedef float   f32x4  __attribute__((ext_vector_type(4)));
typedef short   short8 __attribute__((ext_vector_type(8)));
typedef __bf16  bf16x8 __attribute__((ext_vector_type(8)));
typedef float   float4v __attribute__((ext_vector_type(4)));
typedef unsigned short u16x4 __attribute__((ext_vector_type(4)));

static __device__ __forceinline__ u16 f2b(float f) {
  union { float f; unsigned u; } v; v.f = f;
  unsigned r = (v.u + 0x7fffu + ((v.u >> 16) & 1u)) >> 16;  // RNE
  return (u16)r;
}
static __device__ __forceinline__ float b2f(u16 h) {
  union { unsigned u; float f; } v; v.u = ((unsigned)h) << 16;
  return v.f;
}
static __device__ __forceinline__ f32x4 mfma_bf16(short8 a, short8 b, f32x4 c) {
  return __builtin_amdgcn_mfma_f32_16x16x32_bf16(
      __builtin_bit_cast(bf16x8, a), __builtin_bit_cast(bf16x8, b), c, 0, 0, 0);
}
// async global->LDS, 16B per lane; lds ptr must be wave-uniform base (HW adds lane*16)
static __device__ __forceinline__ void gload_lds16(const u16* g, u16* l) {
  __builtin_amdgcn_global_load_lds(
      (const __attribute__((address_space(1))) unsigned int*)g,
      (__attribute__((address_space(3))) unsigned int*)l, 16, 0, 0);
}

// ---------- problem constants ----------
#define BB 2
#define TT 2048
#define DD 2048
#define NH 16
#define NKVH 4
#define HD 128
#define MM (BB * TT)          // 4096 rows
#define QSTR 3072             // fused QKV projection row: [Q(2048) | K(512) | V(512)]

// ---------- fp32 -> bf16 convert ----------
__global__ __launch_bounds__(256) void cvt_f32_bf16(const float* __restrict__ in,
                                                    u16* __restrict__ out, int n4) {
  int stride = gridDim.x * blockDim.x;
  for (int i = blockIdx.x * blockDim.x + threadIdx.x; i < n4; i += stride) {
    float4v v = ((const float4v*)in)[i];
    u16x4 o;
    o[0] = f2b(v[0]); o[1] = f2b(v[1]); o[2] = f2b(v[2]); o[3] = f2b(v[3]);
    ((u16x4*)out)[i] = o;
  }
}

// ---------- RoPE in-place on bf16 (softmax scale folded in for Q) ----------
__global__ __launch_bounds__(256) void rope_kernel(u16* __restrict__ X,
                                                   const float* __restrict__ rope,
                                                   int n_heads, int rowstr, float scale) {
  int idx = blockIdx.x * 256 + threadIdx.x;
  int i  = idx & 63;
  int h  = (idx >> 6) % n_heads;
  int bt = idx / (64 * n_heads);
  int t  = bt & (TT - 1);
  size_t base = (size_t)bt * rowstr + h * HD + i;
  float x1 = b2f(X[base]);
  float x2 = b2f(X[base + 64]);
  float c = rope[t * 128 + 2 * i];
  float s = rope[t * 128 + 2 * i + 1];
  X[base]      = f2b(scale * (x1 * c - x2 * s));
  X[base + 64] = f2b(scale * (x1 * s + x2 * c));
}

// ---------- GEMM (m97 structure): C[M,N] = A[M,K] * W[N,K]^T ----------
template <bool OUTBF>
__global__ __launch_bounds__(256) void gemm_bt(const u16* __restrict__ A,
                                               const u16* __restrict__ W,
                                               void* __restrict__ Cout,
                                               int M, int N, int K) {
  __shared__ __align__(16) u16 As[128 * 32];
  __shared__ __align__(16) u16 Ws[128 * 32];
  const int tid = threadIdx.x, lane = tid & 63, wid = tid >> 6;
  const int wr = wid >> 1, wc = wid & 1;
  const int brow = blockIdx.y * 128, bcol = blockIdx.x * 128;
  const int l15 = lane & 15, lh = lane >> 4;

  const int c0 = wid * 64 + lane;
  const int c1 = c0 + 256;
  const u16* Ag0 = A + (size_t)(brow + (c0 >> 2)) * K + ((c0 & 3) << 3);
  const u16* Ag1 = A + (size_t)(brow + (c1 >> 2)) * K + ((c1 & 3) << 3);
  const u16* Wg0 = W + (size_t)(bcol + (c0 >> 2)) * K + ((c0 & 3) << 3);
  const u16* Wg1 = W + (size_t)(bcol + (c1 >> 2)) * K + ((c1 & 3) << 3);
  u16* lA0 = &As[(wid * 64) * 8];
  u16* lA1 = &As[(wid * 64 + 256) * 8];
  u16* lW0 = &Ws[(wid * 64) * 8];
  u16* lW1 = &Ws[(wid * 64 + 256) * 8];

  f32x4 acc[4][4];
#pragma unroll
  for (int m = 0; m < 4; ++m)
#pragma unroll
    for (int n = 0; n < 4; ++n) acc[m][n] = (f32x4)0.0f;

  for (int k0 = 0; k0 < K; k0 += 32) {
    __syncthreads();
    gload_lds16(Ag0 + k0, lA0);
    gload_lds16(Ag1 + k0, lA1);
    gload_lds16(Wg0 + k0, lW0);
    gload_lds16(Wg1 + k0, lW1);
    __syncthreads();
    short8 af[4], bfr[4];
#pragma unroll
    for (int m = 0; m < 4; ++m)
      af[m] = *(const short8*)&As[(wr * 64 + m * 16 + l15) * 32 + (lh << 3)];
#pragma unroll
    for (int n = 0; n < 4; ++n)
      bfr[n] = *(const short8*)&Ws[(wc * 64 + n * 16 + l15) * 32 + (lh << 3)];
#pragma unroll
    for (int m = 0; m < 4; ++m)
#pragma unroll
      for (int n = 0; n < 4; ++n)
        acc[m][n] = mfma_bf16(af[m], bfr[n], acc[m][n]);
  }

#pragma unroll
  for (int m = 0; m < 4; ++m)
#pragma unroll
    for (int n = 0; n < 4; ++n)
#pragma unroll
      for (int j = 0; j < 4; ++j) {
        int row = brow + wr * 64 + m * 16 + lh * 4 + j;
        int col = bcol + wc * 64 + n * 16 + l15;
        if (OUTBF)
          ((u16*)Cout)[(size_t)row * N + col] = f2b(acc[m][n][j]);
        else
          ((float*)Cout)[(size_t)row * N + col] = acc[m][n][j];
      }
}

// ---------- fused causal GQA flash attention ----------
// Round-0 per-wave code path (16-row waves, attn_tile, T14 staging) with a
// concurrency-fixed grid: 512 blocks x 8 waves; block = half of qtA (waves
// 0-3) + half of qtB=15-qtA (waves 4-7). 2 blocks/CU (LDS 54.3KB) -> 16
// waves/CU. half=1 blocks take the complementary qpair so each CU's two
// resident blocks sum to uniform staging (50 tiles) and uniform compute.
#define QBLK 128
#define KVBLK 64

static __device__ __forceinline__ void attn_tile(
    const short8* qa, f32x4* o, f32x4& ol, float* mrow,
    int qrow0, int kv0,
    const u16* Ks, const unsigned* Vt32, u16* myP,
    int l15, int lh, short8 ones8) {
  if (kv0 > qrow0 + 15) return;   // fully masked for this wave

  f32x4 s[4];
#pragma unroll
  for (int nt = 0; nt < 4; ++nt) s[nt] = (f32x4)0.0f;
  __builtin_amdgcn_s_setprio(1);
#pragma unroll
  for (int nt = 0; nt < 4; ++nt)
#pragma unroll
    for (int kk = 0; kk < 4; ++kk) {
      short8 kb = *(const short8*)&Ks[(nt * 16 + l15) * 136 + kk * 32 + (lh << 3)];
      s[nt] = mfma_bf16(qa[kk], kb, s[nt]);
    }
  __builtin_amdgcn_s_setprio(0);

  const int qg = qrow0 + lh * 4;
#pragma unroll
  for (int j = 0; j < 4; ++j)
#pragma unroll
    for (int nt = 0; nt < 4; ++nt)
      if (kv0 + nt * 16 + l15 > qg + j) s[nt][j] = -1e30f;

  float mt[4];
#pragma unroll
  for (int j = 0; j < 4; ++j)
    mt[j] = fmaxf(fmaxf(s[0][j], s[1][j]), fmaxf(s[2][j], s[3][j]));
#pragma unroll
  for (int d = 1; d <= 8; d <<= 1)
#pragma unroll
    for (int j = 0; j < 4; ++j) mt[j] = fmaxf(mt[j], __shfl_xor(mt[j], d));

  // defer-max (T13): rescale only when max grew by > 8
  float gmax = mt[0] - mrow[0];
#pragma unroll
  for (int j = 1; j < 4; ++j) gmax = fmaxf(gmax, mt[j] - mrow[j]);
  if (!__all(gmax <= 8.0f)) {
#pragma unroll
    for (int j = 0; j < 4; ++j) {
      float mn = fmaxf(mrow[j], mt[j]);
      float a = __expf(mrow[j] - mn);
      mrow[j] = mn;
      ol[j] *= a;
#pragma unroll
      for (int n = 0; n < 8; ++n) o[n][j] *= a;
    }
  }

  f32x4 p[4];
#pragma unroll
  for (int nt = 0; nt < 4; ++nt)
#pragma unroll
    for (int j = 0; j < 4; ++j) p[nt][j] = __expf(s[nt][j] - mrow[j]);

  // P -> per-wave LDS (transpose to A-frag layout)
#pragma unroll
  for (int nt = 0; nt < 4; ++nt)
#pragma unroll
    for (int j = 0; j < 4; ++j)
      myP[(lh * 4 + j) * 72 + nt * 16 + l15] = f2b(p[nt][j]);

  // PV (+ row-sum via ones-MFMA instead of shuffles)
  __builtin_amdgcn_s_setprio(1);
#pragma unroll
  for (int c = 0; c < 2; ++c) {
    short8 pa = *(const short8*)&myP[l15 * 72 + c * 32 + (lh << 3)];
    ol = mfma_bf16(pa, ones8, ol);
#pragma unroll
    for (int nt2 = 0; nt2 < 8; ++nt2) {
      int d = nt2 * 16 + l15;
      int byteoff = (d * 144 + (c * 32 + lh * 8) * 2) ^ (((d >> 3) & 7) << 4);
      short8 vb = *(const short8*)((const char*)Vt32 + byteoff);
      o[nt2] = mfma_bf16(pa, vb, o[nt2]);
    }
  }
  __builtin_amdgcn_s_setprio(0);
}

__global__ __launch_bounds__(512, 4) void attn_kernel(const u16* __restrict__ QKV,
                                                      u16* __restrict__ Y) {
  __shared__ __align__(16) u16 Ks[KVBLK * 136];      // 17408 B
  __shared__ __align__(16) unsigned Vt32[128 * 36];  // 18432 B
  __shared__ __align__(16) u16 Ps[8][16 * 72];       // 18432 B
  // total 54272 B -> 2 blocks/CU

  const int tid = threadIdx.x, lane = tid & 63, wid = tid >> 6;
  const int l15 = lane & 15, lh = lane >> 4;
  const int bid = blockIdx.x;
  const int half = bid >> 8;                 // 0 or 1 (second dispatch round)
  const int r = bid & 255;
  const int qp_raw = r >> 5;                 // 0..7
  const int qpair = half ? 7 - qp_raw : qp_raw;  // co-resident blocks complement
  const int bh = r & 31;
  const int h = bh & 15;
  const int b = bh >> 4;
  const int kvh = h >> 2;
  const int qtA = qpair, qtB = 15 - qpair;
  const int myqt = (wid < 4) ? qtA : qtB;
  const int row0 = myqt * QBLK + half * 64 + (wid & 3) * 16;  // wave's 16 q rows

  const u16* Kb_ = QKV + (size_t)b * TT * QSTR + DD + kvh * HD;  // K cols
  const u16* Vb_ = Kb_ + NKVH * HD;                              // V cols

  short8 ones8;
#pragma unroll
  for (int e = 0; e < 8; ++e) ones8[e] = (short)0x3F80;  // bf16 1.0

  short8 qa[4];
  {
    const u16* qp = QKV + (size_t)(b * TT + row0 + l15) * QSTR + h * HD + (lh << 3);
#pragma unroll
    for (int kk = 0; kk < 4; ++kk) qa[kk] = *(const short8*)(qp + kk * 32);
  }

  f32x4 o[8];
  f32x4 ol = (f32x4)0.0f;
  float m[4];
#pragma unroll
  for (int n = 0; n < 8; ++n) o[n] = (f32x4)0.0f;
#pragma unroll
  for (int j = 0; j < 4; ++j) m[j] = -1e30f;

  const int ntile = (qtB + 1) * (QBLK / KVBLK);

  // staging registers (T14: issue early, write late)
  short8 kreg0, kreg1, vreg0, vreg1;
  const int srow = tid >> 4;           // 0..31
  const int sc8 = (tid & 15) << 3;

  auto issue = [&](int kv0) {
    kreg0 = *(const short8*)&Kb_[(size_t)(kv0 + srow) * QSTR + sc8];
    kreg1 = *(const short8*)&Kb_[(size_t)(kv0 + 32 + srow) * QSTR + sc8];
    vreg0 = *(const short8*)&Vb_[(size_t)(kv0 + 2 * srow) * QSTR + sc8];
    vreg1 = *(const short8*)&Vb_[(size_t)(kv0 + 2 * srow + 1) * QSTR + sc8];
  };

  issue(0);
  for (int it = 0; it < ntile; ++it) {
    const int kv0 = it * KVBLK;
    __syncthreads();   // previous tile's LDS reads done
    // K rows srow, srow+32 (row-major, pad 136)
    *(short8*)&Ks[srow * 136 + sc8] = kreg0;
    *(short8*)&Ks[(srow + 32) * 136 + sc8] = kreg1;
    // V transposed as u32 kv-pairs, XOR-swizzled
#pragma unroll
    for (int e = 0; e < 8; ++e) {
      int d = sc8 + e;
      unsigned pack = (unsigned)(u16)vreg0[e] | ((unsigned)(u16)vreg1[e] << 16);
      int byteoff = (d * 144 + 4 * srow) ^ (((d >> 3) & 7) << 4);
      *(unsigned*)((char*)Vt32 + byteoff) = pack;
    }
    __syncthreads();   // staged tile visible
    if (it + 1 < ntile) issue(kv0 + KVBLK);  // overlap next loads with compute

    attn_tile(qa, o, ol, m, row0, kv0, Ks, Vt32, &Ps[wid][0], l15, lh, ones8);
  }

  f32x4 inv;
#pragma unroll
  for (int j = 0; j < 4; ++j) inv[j] = __builtin_amdgcn_rcpf(ol[j]);
#pragma unroll
  for (int nt = 0; nt < 8; ++nt)
#pragma unroll
    for (int j = 0; j < 4; ++j)
      Y[(size_t)(b * TT + row0 + lh * 4 + j) * DD + h * HD + nt * 16 + l15] =
          f2b(o[nt][j] * inv[j]);
}

// ---------- launcher ----------
extern "C" void kernel_launch(void* const* d_in, const int* in_sizes, int n_in,
                              void* d_out, int out_size, void* d_ws, size_t ws_size,
                              hipStream_t stream) {
  const float* x    = (const float*)d_in[0];
  const float* rope = (const float*)d_in[1];
  const float* wq   = (const float*)d_in[2];
  const float* wk   = (const float*)d_in[3];
  const float* wv   = (const float*)d_in[4];
  const float* wo   = (const float*)d_in[5];
  float* out = (float*)d_out;

  char* ws = (char*)d_ws;
  u16* xb    = (u16*)ws; ws += (size_t)MM * DD * 2;        // 16.8 MB
  u16* wqkvb = (u16*)ws; ws += (size_t)QSTR * DD * 2;      // 12.6 MB (wq|wk|wv rows)
  u16* wob   = (u16*)ws; ws += (size_t)DD * DD * 2;        //  8.4 MB
  u16* QKVb  = (u16*)ws; ws += (size_t)MM * QSTR * 2;      // 25.2 MB
  u16* Yb    = (u16*)ws;                                   // 16.8 MB

  // 1) converts (wq, wk, wv concatenated into one [3072][2048] weight)
  cvt_f32_bf16<<<2048, 256, 0, stream>>>(x,  xb,  (MM * DD) / 4);
  cvt_f32_bf16<<<2048, 256, 0, stream>>>(wq, wqkvb, (DD * DD) / 4);
  cvt_f32_bf16<<<1024, 256, 0, stream>>>(wk, wqkvb + (size_t)DD * DD, (NKVH * HD * DD) / 4);
  cvt_f32_bf16<<<1024, 256, 0, stream>>>(wv, wqkvb + (size_t)(DD + NKVH * HD) * DD, (NKVH * HD * DD) / 4);
  cvt_f32_bf16<<<2048, 256, 0, stream>>>(wo, wob, (DD * DD) / 4);

  // 2) fused QKV projection: one M=4096, N=3072, K=2048 GEMM
  gemm_bt<true><<<dim3(QSTR / 128, MM / 128), 256, 0, stream>>>(xb, wqkvb, QKVb, MM, QSTR, DD);

  // 3) RoPE (softmax scale folded into Q; V cols untouched)
  rope_kernel<<<(MM * NH * 64) / 256, 256, 0, stream>>>(QKVb, rope, NH, QSTR, 0.08838834764831845f);
  rope_kernel<<<(MM * NKVH * 64) / 256, 256, 0, stream>>>(QKVb + DD, rope, NKVH, QSTR, 1.0f);

  // 4) attention (512 half-qt blocks, 2 blocks/CU, 16 waves/CU)
  attn_kernel<<<512, 512, 0, stream>>>(QKVb, Yb);

  // 5) output projection (fp32 out)
  gemm_bt<false><<<dim3(DD / 128, MM / 128), 256, 0, stream>>>(Yb, wob, out, MM, DD, DD);
}

// Round 5
// 254.099 us; speedup vs baseline: 1.1373x; 1.1373x over previous
//
#include <hip/hip_runtime.h>

// ---------- types & helpers ----------
typedef unsigned short u16;
typedef float   f32x4  __attribute__((ext_vector_type(4)));
typedef short   short8 __attribute__((ext_vector_type(8)));
typedef __bf16  bf16x8 __attribute__((ext_vector_type(8)));
typedef float   float4v __attribute__((ext_vector_type(4)));
typedef unsigned short u16x4 __attribute__((ext_vector_type(4)));

static __device__ __forceinline__ u16 f2b(float f) {
  union { float f; unsigned u; } v; v.f = f;
  unsigned r = (v.u + 0x7fffu + ((v.u >> 16) & 1u)) >> 16;  // RNE
  return (u16)r;
}
static __device__ __forceinline__ float b2f(u16 h) {
  union { unsigned u; float f; } v; v.u = ((unsigned)h) << 16;
  return v.f;
}
static __device__ __forceinline__ f32x4 mfma_bf16(short8 a, short8 b, f32x4 c) {
  return __builtin_amdgcn_mfma_f32_16x16x32_bf16(
      __builtin_bit_cast(bf16x8, a), __builtin_bit_cast(bf16x8, b), c, 0, 0, 0);
}
// async global->LDS, 16B per lane; lds ptr must be wave-uniform base (HW adds lane*16)
static __device__ __forceinline__ void gload_lds16(const u16* g, u16* l) {
  __builtin_amdgcn_global_load_lds(
      (const __attribute__((address_space(1))) unsigned int*)g,
      (__attribute__((address_space(3))) unsigned int*)l, 16, 0, 0);
}

// ---------- problem constants ----------
#define BB 2
#define TT 2048
#define DD 2048
#define NH 16
#define NKVH 4
#define HD 128
#define MM (BB * TT)          // 4096 rows
#define QSTR 3072             // fused QKV projection row: [Q(2048) | K(512) | V(512)]

// ---------- fp32 -> bf16 convert ----------
__global__ __launch_bounds__(256) void cvt_f32_bf16(const float* __restrict__ in,
                                                    u16* __restrict__ out, int n4) {
  int stride = gridDim.x * blockDim.x;
  for (int i = blockIdx.x * blockDim.x + threadIdx.x; i < n4; i += stride) {
    float4v v = ((const float4v*)in)[i];
    u16x4 o;
    o[0] = f2b(v[0]); o[1] = f2b(v[1]); o[2] = f2b(v[2]); o[3] = f2b(v[3]);
    ((u16x4*)out)[i] = o;
  }
}

// ---------- RoPE in-place on bf16 (softmax scale folded in for Q) ----------
__global__ __launch_bounds__(256) void rope_kernel(u16* __restrict__ X,
                                                   const float* __restrict__ rope,
                                                   int n_heads, int rowstr, float scale) {
  int idx = blockIdx.x * 256 + threadIdx.x;
  int i  = idx & 63;
  int h  = (idx >> 6) % n_heads;
  int bt = idx / (64 * n_heads);
  int t  = bt & (TT - 1);
  size_t base = (size_t)bt * rowstr + h * HD + i;
  float x1 = b2f(X[base]);
  float x2 = b2f(X[base + 64]);
  float c = rope[t * 128 + 2 * i];
  float s = rope[t * 128 + 2 * i + 1];
  X[base]      = f2b(scale * (x1 * c - x2 * s));
  X[base + 64] = f2b(scale * (x1 * s + x2 * c));
}

// ---------- GEMM (m97 structure): C[M,N] = A[M,K] * W[N,K]^T ----------
template <bool OUTBF>
__global__ __launch_bounds__(256) void gemm_bt(const u16* __restrict__ A,
                                               const u16* __restrict__ W,
                                               void* __restrict__ Cout,
                                               int M, int N, int K) {
  __shared__ __align__(16) u16 As[128 * 32];
  __shared__ __align__(16) u16 Ws[128 * 32];
  const int tid = threadIdx.x, lane = tid & 63, wid = tid >> 6;
  const int wr = wid >> 1, wc = wid & 1;
  const int brow = blockIdx.y * 128, bcol = blockIdx.x * 128;
  const int l15 = lane & 15, lh = lane >> 4;

  const int c0 = wid * 64 + lane;
  const int c1 = c0 + 256;
  const u16* Ag0 = A + (size_t)(brow + (c0 >> 2)) * K + ((c0 & 3) << 3);
  const u16* Ag1 = A + (size_t)(brow + (c1 >> 2)) * K + ((c1 & 3) << 3);
  const u16* Wg0 = W + (size_t)(bcol + (c0 >> 2)) * K + ((c0 & 3) << 3);
  const u16* Wg1 = W + (size_t)(bcol + (c1 >> 2)) * K + ((c1 & 3) << 3);
  u16* lA0 = &As[(wid * 64) * 8];
  u16* lA1 = &As[(wid * 64 + 256) * 8];
  u16* lW0 = &Ws[(wid * 64) * 8];
  u16* lW1 = &Ws[(wid * 64 + 256) * 8];

  f32x4 acc[4][4];
#pragma unroll
  for (int m = 0; m < 4; ++m)
#pragma unroll
    for (int n = 0; n < 4; ++n) acc[m][n] = (f32x4)0.0f;

  for (int k0 = 0; k0 < K; k0 += 32) {
    __syncthreads();
    gload_lds16(Ag0 + k0, lA0);
    gload_lds16(Ag1 + k0, lA1);
    gload_lds16(Wg0 + k0, lW0);
    gload_lds16(Wg1 + k0, lW1);
    __syncthreads();
    short8 af[4], bfr[4];
#pragma unroll
    for (int m = 0; m < 4; ++m)
      af[m] = *(const short8*)&As[(wr * 64 + m * 16 + l15) * 32 + (lh << 3)];
#pragma unroll
    for (int n = 0; n < 4; ++n)
      bfr[n] = *(const short8*)&Ws[(wc * 64 + n * 16 + l15) * 32 + (lh << 3)];
#pragma unroll
    for (int m = 0; m < 4; ++m)
#pragma unroll
      for (int n = 0; n < 4; ++n)
        acc[m][n] = mfma_bf16(af[m], bfr[n], acc[m][n]);
  }

#pragma unroll
  for (int m = 0; m < 4; ++m)
#pragma unroll
    for (int n = 0; n < 4; ++n)
#pragma unroll
      for (int j = 0; j < 4; ++j) {
        int row = brow + wr * 64 + m * 16 + lh * 4 + j;
        int col = bcol + wc * 64 + n * 16 + l15;
        if (OUTBF)
          ((u16*)Cout)[(size_t)row * N + col] = f2b(acc[m][n][j]);
        else
          ((float*)Cout)[(size_t)row * N + col] = acc[m][n][j];
      }
}

// ---------- fused causal GQA flash attention ----------
// R0 shell (256 blocks x 8 waves, 1 block/CU, uniform ntile, T14 staging)
// + R3 merged 32-row waves: each wave owns 32 contiguous q-rows (2 groups of
// 16) and reads every K AND V fragment ONCE for both groups (44% LDS-read
// cut). Both P tiles live simultaneously -> Ps[8][2], LDS 72.7KB (<160KB HW).
// Block = qtA (waves 0-3) + qtB = 15-qtA (waves 4-7), so ntile is uniform
// per block and compute is uniform per CU.
#define QBLK 128
#define KVBLK 64

__global__ __launch_bounds__(512, 2) void attn_kernel(const u16* __restrict__ QKV,
                                                      u16* __restrict__ Y) {
  __shared__ __align__(16) u16 Ks[KVBLK * 136];      // 17408 B
  __shared__ __align__(16) unsigned Vt32[128 * 36];  // 18432 B
  __shared__ __align__(16) u16 Ps[8][2][16 * 72];    // 36864 B
  // total 72704 B -> 1 block/CU (grid 256 = #CU)

  const int tid = threadIdx.x, lane = tid & 63, wid = tid >> 6;  // wid 0..7
  const int l15 = lane & 15, lh = lane >> 4;
  const int bid = blockIdx.x;
  const int qpair = bid >> 5;                 // 0..7
  const int bh = bid & 31;
  const int h = bh & 15;
  const int b = bh >> 4;
  const int kvh = h >> 2;
  const int qtA = qpair, qtB = 15 - qpair;
  const int myqt = (wid < 4) ? qtA : qtB;
  const int row0 = myqt * QBLK + (wid & 3) * 32;   // wave's 32 q rows

  const u16* Kb_ = QKV + (size_t)b * TT * QSTR + DD + kvh * HD;  // K cols
  const u16* Vb_ = Kb_ + NKVH * HD;                              // V cols

  short8 ones8;
#pragma unroll
  for (int e = 0; e < 8; ++e) ones8[e] = (short)0x3F80;  // bf16 1.0

  short8 qa[2][4];
#pragma unroll
  for (int g = 0; g < 2; ++g) {
    const u16* qp = QKV + (size_t)(b * TT + row0 + g * 16 + l15) * QSTR + h * HD + (lh << 3);
#pragma unroll
    for (int kk = 0; kk < 4; ++kk) qa[g][kk] = *(const short8*)(qp + kk * 32);
  }

  f32x4 o[2][8];
  f32x4 ol[2];
  float m[2][4];
#pragma unroll
  for (int g = 0; g < 2; ++g) {
    ol[g] = (f32x4)0.0f;
#pragma unroll
    for (int n = 0; n < 8; ++n) o[g][n] = (f32x4)0.0f;
#pragma unroll
    for (int j = 0; j < 4; ++j) m[g][j] = -1e30f;
  }

  u16* myP0 = &Ps[wid][0][0];
  u16* myP1 = &Ps[wid][1][0];

  const int ntile = (qtB + 1) * (QBLK / KVBLK);

  // staging registers (T14: issue early, write late); 512 threads cover the tile
  short8 kreg0, kreg1, vreg0, vreg1;
  const int srow = tid >> 4;           // 0..31
  const int sc8 = (tid & 15) << 3;

  auto issue = [&](int kv0) {
    kreg0 = *(const short8*)&Kb_[(size_t)(kv0 + srow) * QSTR + sc8];
    kreg1 = *(const short8*)&Kb_[(size_t)(kv0 + 32 + srow) * QSTR + sc8];
    vreg0 = *(const short8*)&Vb_[(size_t)(kv0 + 2 * srow) * QSTR + sc8];
    vreg1 = *(const short8*)&Vb_[(size_t)(kv0 + 2 * srow + 1) * QSTR + sc8];
  };

  // per-group softmax + P write (16-lane-group rowmax, defer-max T13)
  auto soft = [&](f32x4* sg, float* mg, f32x4& olg, f32x4* og, u16* myP) {
    float mt[4];
#pragma unroll
    for (int j = 0; j < 4; ++j)
      mt[j] = fmaxf(fmaxf(sg[0][j], sg[1][j]), fmaxf(sg[2][j], sg[3][j]));
#pragma unroll
    for (int d = 1; d <= 8; d <<= 1)
#pragma unroll
      for (int j = 0; j < 4; ++j) mt[j] = fmaxf(mt[j], __shfl_xor(mt[j], d));

    float gmax = mt[0] - mg[0];
#pragma unroll
    for (int j = 1; j < 4; ++j) gmax = fmaxf(gmax, mt[j] - mg[j]);
    if (!__all(gmax <= 8.0f)) {
#pragma unroll
      for (int j = 0; j < 4; ++j) {
        float mn = fmaxf(mg[j], mt[j]);
        float a = __expf(mg[j] - mn);
        mg[j] = mn;
        olg[j] *= a;
#pragma unroll
        for (int n = 0; n < 8; ++n) og[n][j] *= a;
      }
    }
#pragma unroll
    for (int nt = 0; nt < 4; ++nt)
#pragma unroll
      for (int j = 0; j < 4; ++j)
        myP[(lh * 4 + j) * 72 + nt * 16 + l15] = f2b(__expf(sg[nt][j] - mg[j]));
  };

  issue(0);
  for (int it = 0; it < ntile; ++it) {
    const int kv0 = it * KVBLK;
    __syncthreads();   // previous tile's LDS reads done
    // K rows srow, srow+32 (row-major, pad 136)
    *(short8*)&Ks[srow * 136 + sc8] = kreg0;
    *(short8*)&Ks[(srow + 32) * 136 + sc8] = kreg1;
    // V transposed as u32 kv-pairs, XOR-swizzled
#pragma unroll
    for (int e = 0; e < 8; ++e) {
      int d = sc8 + e;
      unsigned pack = (unsigned)(u16)vreg0[e] | ((unsigned)(u16)vreg1[e] << 16);
      int byteoff = (d * 144 + 4 * srow) ^ (((d >> 3) & 7) << 4);
      *(unsigned*)((char*)Vt32 + byteoff) = pack;
    }
    __syncthreads();   // staged tile visible
    if (it + 1 < ntile) issue(kv0 + KVBLK);  // overlap next loads with compute

    if (kv0 > row0 + 31) continue;           // wave fully masked
    const bool a0 = (kv0 <= row0 + 15);      // lower 16 rows still active?

    // ---- QK^T: each K fragment read once, applied to active groups
    f32x4 s[2][4];
#pragma unroll
    for (int g = 0; g < 2; ++g)
#pragma unroll
      for (int nt = 0; nt < 4; ++nt) s[g][nt] = (f32x4)0.0f;

    __builtin_amdgcn_s_setprio(1);
    if (a0) {
#pragma unroll
      for (int nt = 0; nt < 4; ++nt) {
        const u16* krow = &Ks[(nt * 16 + l15) * 136 + (lh << 3)];
#pragma unroll
        for (int kk = 0; kk < 4; ++kk) {
          short8 kb = *(const short8*)(krow + kk * 32);
          s[0][nt] = mfma_bf16(qa[0][kk], kb, s[0][nt]);
          s[1][nt] = mfma_bf16(qa[1][kk], kb, s[1][nt]);
        }
      }
    } else {
#pragma unroll
      for (int nt = 0; nt < 4; ++nt) {
        const u16* krow = &Ks[(nt * 16 + l15) * 136 + (lh << 3)];
#pragma unroll
        for (int kk = 0; kk < 4; ++kk) {
          short8 kb = *(const short8*)(krow + kk * 32);
          s[1][nt] = mfma_bf16(qa[1][kk], kb, s[1][nt]);
        }
      }
    }
    __builtin_amdgcn_s_setprio(0);

    // ---- causal mask (only on tiles that straddle each group's diagonal)
    if (a0 && kv0 + 63 > row0) {
      const int qg = row0 + lh * 4;
#pragma unroll
      for (int j = 0; j < 4; ++j)
#pragma unroll
        for (int nt = 0; nt < 4; ++nt)
          if (kv0 + nt * 16 + l15 > qg + j) s[0][nt][j] = -1e30f;
    }
    if (kv0 + 63 > row0 + 16) {
      const int qg = row0 + 16 + lh * 4;
#pragma unroll
      for (int j = 0; j < 4; ++j)
#pragma unroll
        for (int nt = 0; nt < 4; ++nt)
          if (kv0 + nt * 16 + l15 > qg + j) s[1][nt][j] = -1e30f;
    }

    // ---- softmax + P for active groups
    if (a0) soft(s[0], m[0], ol[0], o[0], myP0);
    soft(s[1], m[1], ol[1], o[1], myP1);

    // ---- PV: each V fragment read once, applied to active groups
    __builtin_amdgcn_s_setprio(1);
    if (a0) {
#pragma unroll
      for (int c = 0; c < 2; ++c) {
        short8 pa0 = *(const short8*)&myP0[l15 * 72 + c * 32 + (lh << 3)];
        short8 pa1 = *(const short8*)&myP1[l15 * 72 + c * 32 + (lh << 3)];
        ol[0] = mfma_bf16(pa0, ones8, ol[0]);
        ol[1] = mfma_bf16(pa1, ones8, ol[1]);
#pragma unroll
        for (int nt2 = 0; nt2 < 8; ++nt2) {
          int d = nt2 * 16 + l15;
          int byteoff = (d * 144 + (c * 32 + lh * 8) * 2) ^ (((d >> 3) & 7) << 4);
          short8 vb = *(const short8*)((const char*)Vt32 + byteoff);
          o[0][nt2] = mfma_bf16(pa0, vb, o[0][nt2]);
          o[1][nt2] = mfma_bf16(pa1, vb, o[1][nt2]);
        }
      }
    } else {
#pragma unroll
      for (int c = 0; c < 2; ++c) {
        short8 pa1 = *(const short8*)&myP1[l15 * 72 + c * 32 + (lh << 3)];
        ol[1] = mfma_bf16(pa1, ones8, ol[1]);
#pragma unroll
        for (int nt2 = 0; nt2 < 8; ++nt2) {
          int d = nt2 * 16 + l15;
          int byteoff = (d * 144 + (c * 32 + lh * 8) * 2) ^ (((d >> 3) & 7) << 4);
          short8 vb = *(const short8*)((const char*)Vt32 + byteoff);
          o[1][nt2] = mfma_bf16(pa1, vb, o[1][nt2]);
        }
      }
    }
    __builtin_amdgcn_s_setprio(0);
  }

  // ---- epilogue
#pragma unroll
  for (int g = 0; g < 2; ++g) {
    f32x4 inv;
#pragma unroll
    for (int j = 0; j < 4; ++j) inv[j] = __builtin_amdgcn_rcpf(ol[g][j]);
#pragma unroll
    for (int nt2 = 0; nt2 < 8; ++nt2)
#pragma unroll
      for (int j = 0; j < 4; ++j)
        Y[(size_t)(b * TT + row0 + g * 16 + lh * 4 + j) * DD + h * HD + nt2 * 16 + l15] =
            f2b(o[g][nt2][j] * inv[j]);
  }
}

// ---------- launcher ----------
extern "C" void kernel_launch(void* const* d_in, const int* in_sizes, int n_in,
                              void* d_out, int out_size, void* d_ws, size_t ws_size,
                              hipStream_t stream) {
  const float* x    = (const float*)d_in[0];
  const float* rope = (const float*)d_in[1];
  const float* wq   = (const float*)d_in[2];
  const float* wk   = (const float*)d_in[3];
  const float* wv   = (const float*)d_in[4];
  const float* wo   = (const float*)d_in[5];
  float* out = (float*)d_out;

  char* ws = (char*)d_ws;
  u16* xb    = (u16*)ws; ws += (size_t)MM * DD * 2;        // 16.8 MB
  u16* wqkvb = (u16*)ws; ws += (size_t)QSTR * DD * 2;      // 12.6 MB (wq|wk|wv rows)
  u16* wob   = (u16*)ws; ws += (size_t)DD * DD * 2;        //  8.4 MB
  u16* QKVb  = (u16*)ws; ws += (size_t)MM * QSTR * 2;      // 25.2 MB
  u16* Yb    = (u16*)ws;                                   // 16.8 MB

  // 1) converts (wq, wk, wv concatenated into one [3072][2048] weight)
  cvt_f32_bf16<<<2048, 256, 0, stream>>>(x,  xb,  (MM * DD) / 4);
  cvt_f32_bf16<<<2048, 256, 0, stream>>>(wq, wqkvb, (DD * DD) / 4);
  cvt_f32_bf16<<<1024, 256, 0, stream>>>(wk, wqkvb + (size_t)DD * DD, (NKVH * HD * DD) / 4);
  cvt_f32_bf16<<<1024, 256, 0, stream>>>(wv, wqkvb + (size_t)(DD + NKVH * HD) * DD, (NKVH * HD * DD) / 4);
  cvt_f32_bf16<<<2048, 256, 0, stream>>>(wo, wob, (DD * DD) / 4);

  // 2) fused QKV projection: one M=4096, N=3072, K=2048 GEMM
  gemm_bt<true><<<dim3(QSTR / 128, MM / 128), 256, 0, stream>>>(xb, wqkvb, QKVb, MM, QSTR, DD);

  // 3) RoPE (softmax scale folded into Q; V cols untouched)
  rope_kernel<<<(MM * NH * 64) / 256, 256, 0, stream>>>(QKVb, rope, NH, QSTR, 0.08838834764831845f);
  rope_kernel<<<(MM * NKVH * 64) / 256, 256, 0, stream>>>(QKVb + DD, rope, NKVH, QSTR, 1.0f);

  // 4) attention (256 blocks, 8 waves, merged 32-row waves, shared K+V frags)
  attn_kernel<<<256, 512, 0, stream>>>(QKVb, Yb);

  // 5) output projection (fp32 out)
  gemm_bt<false><<<dim3(DD / 128, MM / 128), 256, 0, stream>>>(Yb, wob, out, MM, DD, DD);
}

// Round 6
// 232.852 us; speedup vs baseline: 1.2411x; 1.0912x over previous
//
#include <hip/hip_runtime.h>

// ---------- types & helpers ----------
typedef unsigned short u16;
typedef float   f32x4  __attribute__((ext_vector_type(4)));
typedef short   short8 __attribute__((ext_vector_type(8)));
typedef __bf16  bf16x8 __attribute__((ext_vector_type(8)));
typedef float   float4v __attribute__((ext_vector_type(4)));
typedef unsigned short u16x4 __attribute__((ext_vector_type(4)));

static __device__ __forceinline__ u16 f2b(float f) {
  union { float f; unsigned u; } v; v.f = f;
  unsigned r = (v.u + 0x7fffu + ((v.u >> 16) & 1u)) >> 16;  // RNE
  return (u16)r;
}
static __device__ __forceinline__ float b2f(u16 h) {
  union { unsigned u; float f; } v; v.u = ((unsigned)h) << 16;
  return v.f;
}
static __device__ __forceinline__ f32x4 mfma_bf16(short8 a, short8 b, f32x4 c) {
  return __builtin_amdgcn_mfma_f32_16x16x32_bf16(
      __builtin_bit_cast(bf16x8, a), __builtin_bit_cast(bf16x8, b), c, 0, 0, 0);
}
// async global->LDS, 16B per lane; lds ptr must be wave-uniform base (HW adds lane*16)
static __device__ __forceinline__ void gload_lds16(const u16* g, u16* l) {
  __builtin_amdgcn_global_load_lds(
      (const __attribute__((address_space(1))) unsigned int*)g,
      (__attribute__((address_space(3))) unsigned int*)l, 16, 0, 0);
}

// ---------- problem constants ----------
#define BB 2
#define TT 2048
#define DD 2048
#define NH 16
#define NKVH 4
#define HD 128
#define MM (BB * TT)          // 4096 rows
#define QSTR 3072             // fused QKV projection row: [Q(2048) | K(512) | V(512)]

// ---------- fused fp32 -> bf16 convert (all 5 tensors, 1 launch) ----------
// regions (in float4 units): x | wq | wk | wv | wo. All boundaries are
// multiples of 256 so branches are wave-uniform.
#define N4_X   ((MM * DD) / 4)          // 2,097,152
#define N4_WQ  ((DD * DD) / 4)          // 1,048,576
#define N4_WKV ((NKVH * HD * DD) / 4)   //   262,144
#define N4_WO  ((DD * DD) / 4)          // 1,048,576
#define N4_TOT (N4_X + N4_WQ + 2 * N4_WKV + N4_WO)

__global__ __launch_bounds__(256) void cvt_all(const float* __restrict__ x,
                                               const float* __restrict__ wq,
                                               const float* __restrict__ wk,
                                               const float* __restrict__ wv,
                                               const float* __restrict__ wo,
                                               u16* __restrict__ xb,
                                               u16* __restrict__ wqkvb,
                                               u16* __restrict__ wob) {
  int stride = gridDim.x * blockDim.x;
  for (int i = blockIdx.x * blockDim.x + threadIdx.x; i < N4_TOT; i += stride) {
    const float4v* src;
    u16x4* dst;
    int off;
    if (i < N4_X) {
      src = (const float4v*)x; dst = (u16x4*)xb; off = i;
    } else if (i < N4_X + N4_WQ) {
      src = (const float4v*)wq; dst = (u16x4*)wqkvb; off = i - N4_X;
    } else if (i < N4_X + N4_WQ + N4_WKV) {
      src = (const float4v*)wk; dst = (u16x4*)wqkvb + N4_WQ; off = i - (N4_X + N4_WQ);
    } else if (i < N4_X + N4_WQ + 2 * N4_WKV) {
      src = (const float4v*)wv; dst = (u16x4*)wqkvb + N4_WQ + N4_WKV;
      off = i - (N4_X + N4_WQ + N4_WKV);
    } else {
      src = (const float4v*)wo; dst = (u16x4*)wob; off = i - (N4_X + N4_WQ + 2 * N4_WKV);
    }
    float4v v = src[off];
    u16x4 o;
    o[0] = f2b(v[0]); o[1] = f2b(v[1]); o[2] = f2b(v[2]); o[3] = f2b(v[3]);
    dst[off] = o;
  }
}

// ---------- fused RoPE (Q + K in one launch; softmax scale folded into Q) ----------
#define ROPE_QN (MM * NH * 64)  // 4,194,304

static __device__ __forceinline__ void rope_one(u16* X, const float* rope,
                                                int idx, int n_heads, float scale) {
  int i  = idx & 63;
  int h  = (idx >> 6) % n_heads;
  int bt = idx / (64 * n_heads);
  int t  = bt & (TT - 1);
  size_t base = (size_t)bt * QSTR + h * HD + i;
  float x1 = b2f(X[base]);
  float x2 = b2f(X[base + 64]);
  float c = rope[t * 128 + 2 * i];
  float s = rope[t * 128 + 2 * i + 1];
  X[base]      = f2b(scale * (x1 * c - x2 * s));
  X[base + 64] = f2b(scale * (x1 * s + x2 * c));
}

__global__ __launch_bounds__(256) void rope_all(u16* __restrict__ QKV,
                                                const float* __restrict__ rope) {
  int idx = blockIdx.x * 256 + threadIdx.x;
  if (idx < ROPE_QN)
    rope_one(QKV, rope, idx, NH, 0.08838834764831845f);
  else
    rope_one(QKV + DD, rope, idx - ROPE_QN, NKVH, 1.0f);
}

// ---------- GEMM (m97 structure): C[M,N] = A[M,K] * W[N,K]^T ----------
template <bool OUTBF>
__global__ __launch_bounds__(256) void gemm_bt(const u16* __restrict__ A,
                                               const u16* __restrict__ W,
                                               void* __restrict__ Cout,
                                               int M, int N, int K) {
  __shared__ __align__(16) u16 As[128 * 32];
  __shared__ __align__(16) u16 Ws[128 * 32];
  const int tid = threadIdx.x, lane = tid & 63, wid = tid >> 6;
  const int wr = wid >> 1, wc = wid & 1;
  const int brow = blockIdx.y * 128, bcol = blockIdx.x * 128;
  const int l15 = lane & 15, lh = lane >> 4;

  const int c0 = wid * 64 + lane;
  const int c1 = c0 + 256;
  const u16* Ag0 = A + (size_t)(brow + (c0 >> 2)) * K + ((c0 & 3) << 3);
  const u16* Ag1 = A + (size_t)(brow + (c1 >> 2)) * K + ((c1 & 3) << 3);
  const u16* Wg0 = W + (size_t)(bcol + (c0 >> 2)) * K + ((c0 & 3) << 3);
  const u16* Wg1 = W + (size_t)(bcol + (c1 >> 2)) * K + ((c1 & 3) << 3);
  u16* lA0 = &As[(wid * 64) * 8];
  u16* lA1 = &As[(wid * 64 + 256) * 8];
  u16* lW0 = &Ws[(wid * 64) * 8];
  u16* lW1 = &Ws[(wid * 64 + 256) * 8];

  f32x4 acc[4][4];
#pragma unroll
  for (int m = 0; m < 4; ++m)
#pragma unroll
    for (int n = 0; n < 4; ++n) acc[m][n] = (f32x4)0.0f;

  for (int k0 = 0; k0 < K; k0 += 32) {
    __syncthreads();
    gload_lds16(Ag0 + k0, lA0);
    gload_lds16(Ag1 + k0, lA1);
    gload_lds16(Wg0 + k0, lW0);
    gload_lds16(Wg1 + k0, lW1);
    __syncthreads();
    short8 af[4], bfr[4];
#pragma unroll
    for (int m = 0; m < 4; ++m)
      af[m] = *(const short8*)&As[(wr * 64 + m * 16 + l15) * 32 + (lh << 3)];
#pragma unroll
    for (int n = 0; n < 4; ++n)
      bfr[n] = *(const short8*)&Ws[(wc * 64 + n * 16 + l15) * 32 + (lh << 3)];
#pragma unroll
    for (int m = 0; m < 4; ++m)
#pragma unroll
      for (int n = 0; n < 4; ++n)
        acc[m][n] = mfma_bf16(af[m], bfr[n], acc[m][n]);
  }

#pragma unroll
  for (int m = 0; m < 4; ++m)
#pragma unroll
    for (int n = 0; n < 4; ++n)
#pragma unroll
      for (int j = 0; j < 4; ++j) {
        int row = brow + wr * 64 + m * 16 + lh * 4 + j;
        int col = bcol + wc * 64 + n * 16 + l15;
        if (OUTBF)
          ((u16*)Cout)[(size_t)row * N + col] = f2b(acc[m][n][j]);
        else
          ((float*)Cout)[(size_t)row * N + col] = acc[m][n][j];
      }
}

// ---------- fused causal GQA flash attention ----------
// R0-exact structure (best measured: 95 µs): 256 blocks x 8 waves, paired
// q-tiles (qb, 15-qb) -> uniform 34 tile-units/wave, per-wave 16-row
// attn_tile, T14 staging. Only change: KVBLK 64->128 (two 64-row
// sub-buffers per barrier pair) to halve barrier/staging boundaries.
#define QBLK 128
#define KVBLK 128

static __device__ __forceinline__ void attn_tile(
    const short8* qa, f32x4* o, f32x4& ol, float* mrow,
    int qrow0, int kv0,
    const u16* Ks, const unsigned* Vt32, u16* myP,
    int l15, int lh, short8 ones8) {
  if (kv0 > qrow0 + 15) return;   // fully masked for this wave

  f32x4 s[4];
#pragma unroll
  for (int nt = 0; nt < 4; ++nt) s[nt] = (f32x4)0.0f;
  __builtin_amdgcn_s_setprio(1);
#pragma unroll
  for (int nt = 0; nt < 4; ++nt)
#pragma unroll
    for (int kk = 0; kk < 4; ++kk) {
      short8 kb = *(const short8*)&Ks[(nt * 16 + l15) * 136 + kk * 32 + (lh << 3)];
      s[nt] = mfma_bf16(qa[kk], kb, s[nt]);
    }
  __builtin_amdgcn_s_setprio(0);

  const int qg = qrow0 + lh * 4;
#pragma unroll
  for (int j = 0; j < 4; ++j)
#pragma unroll
    for (int nt = 0; nt < 4; ++nt)
      if (kv0 + nt * 16 + l15 > qg + j) s[nt][j] = -1e30f;

  float mt[4];
#pragma unroll
  for (int j = 0; j < 4; ++j)
    mt[j] = fmaxf(fmaxf(s[0][j], s[1][j]), fmaxf(s[2][j], s[3][j]));
#pragma unroll
  for (int d = 1; d <= 8; d <<= 1)
#pragma unroll
    for (int j = 0; j < 4; ++j) mt[j] = fmaxf(mt[j], __shfl_xor(mt[j], d));

  // defer-max (T13): rescale only when max grew by > 8
  float gmax = mt[0] - mrow[0];
#pragma unroll
  for (int j = 1; j < 4; ++j) gmax = fmaxf(gmax, mt[j] - mrow[j]);
  if (!__all(gmax <= 8.0f)) {
#pragma unroll
    for (int j = 0; j < 4; ++j) {
      float mn = fmaxf(mrow[j], mt[j]);
      float a = __expf(mrow[j] - mn);
      mrow[j] = mn;
      ol[j] *= a;
#pragma unroll
      for (int n = 0; n < 8; ++n) o[n][j] *= a;
    }
  }

  f32x4 p[4];
#pragma unroll
  for (int nt = 0; nt < 4; ++nt)
#pragma unroll
    for (int j = 0; j < 4; ++j) p[nt][j] = __expf(s[nt][j] - mrow[j]);

  // P -> per-wave LDS (transpose to A-frag layout)
#pragma unroll
  for (int nt = 0; nt < 4; ++nt)
#pragma unroll
    for (int j = 0; j < 4; ++j)
      myP[(lh * 4 + j) * 72 + nt * 16 + l15] = f2b(p[nt][j]);

  // PV (+ row-sum via ones-MFMA instead of shuffles)
  __builtin_amdgcn_s_setprio(1);
#pragma unroll
  for (int c = 0; c < 2; ++c) {
    short8 pa = *(const short8*)&myP[l15 * 72 + c * 32 + (lh << 3)];
    ol = mfma_bf16(pa, ones8, ol);
#pragma unroll
    for (int nt2 = 0; nt2 < 8; ++nt2) {
      int d = nt2 * 16 + l15;
      int byteoff = (d * 144 + (c * 32 + lh * 8) * 2) ^ (((d >> 3) & 7) << 4);
      short8 vb = *(const short8*)((const char*)Vt32 + byteoff);
      o[nt2] = mfma_bf16(pa, vb, o[nt2]);
    }
  }
  __builtin_amdgcn_s_setprio(0);
}

__global__ __launch_bounds__(512) void attn_kernel(const u16* __restrict__ QKV,
                                                   u16* __restrict__ Y) {
  __shared__ __align__(16) u16 Ks[2][64 * 136];        // 2 x 17408 B
  __shared__ __align__(16) unsigned Vt32[2][128 * 36]; // 2 x 18432 B
  __shared__ __align__(16) u16 Ps[8][16 * 72];         // 18432 B
  // total 90112 B -> 1 block/CU

  const int tid = threadIdx.x, lane = tid & 63, wid = tid >> 6;
  const int l15 = lane & 15, lh = lane >> 4;
  const int bid = blockIdx.x;
  const int qpair = bid & 7;
  const int h = (bid >> 3) & 15;
  const int b = bid >> 7;
  const int kvh = h >> 2;
  const int qtA = qpair, qtB = 15 - qpair;
  const int rowA = qtA * QBLK + wid * 16;
  const int rowB = qtB * QBLK + wid * 16;

  const u16* Kb_ = QKV + (size_t)b * TT * QSTR + DD + kvh * HD;  // K cols
  const u16* Vb_ = Kb_ + NKVH * HD;                              // V cols

  short8 ones8;
#pragma unroll
  for (int e = 0; e < 8; ++e) ones8[e] = (short)0x3F80;  // bf16 1.0

  short8 qaA[4], qaB[4];
  {
    const u16* qA = QKV + (size_t)(b * TT + rowA + l15) * QSTR + h * HD + (lh << 3);
    const u16* qB = QKV + (size_t)(b * TT + rowB + l15) * QSTR + h * HD + (lh << 3);
#pragma unroll
    for (int kk = 0; kk < 4; ++kk) {
      qaA[kk] = *(const short8*)(qA + kk * 32);
      qaB[kk] = *(const short8*)(qB + kk * 32);
    }
  }

  f32x4 oA[8], oB[8];
  f32x4 olA = (f32x4)0.0f, olB = (f32x4)0.0f;
  float mA[4], mB[4];
#pragma unroll
  for (int n = 0; n < 8; ++n) { oA[n] = (f32x4)0.0f; oB[n] = (f32x4)0.0f; }
#pragma unroll
  for (int j = 0; j < 4; ++j) { mA[j] = -1e30f; mB[j] = -1e30f; }

  const int kvend = (qtB + 1) * QBLK;   // multiple of 128

  // staging registers (T14: issue early, write late); 128 KV rows per pass
  short8 kreg[4], vreg[4];
  const int srow = tid >> 4;           // 0..31
  const int sc8 = (tid & 15) << 3;

  auto issue = [&](int kv0) {
    kreg[0] = *(const short8*)&Kb_[(size_t)(kv0 + srow) * QSTR + sc8];
    kreg[1] = *(const short8*)&Kb_[(size_t)(kv0 + 32 + srow) * QSTR + sc8];
    kreg[2] = *(const short8*)&Kb_[(size_t)(kv0 + 64 + srow) * QSTR + sc8];
    kreg[3] = *(const short8*)&Kb_[(size_t)(kv0 + 96 + srow) * QSTR + sc8];
    vreg[0] = *(const short8*)&Vb_[(size_t)(kv0 + 2 * srow) * QSTR + sc8];
    vreg[1] = *(const short8*)&Vb_[(size_t)(kv0 + 2 * srow + 1) * QSTR + sc8];
    vreg[2] = *(const short8*)&Vb_[(size_t)(kv0 + 64 + 2 * srow) * QSTR + sc8];
    vreg[3] = *(const short8*)&Vb_[(size_t)(kv0 + 64 + 2 * srow + 1) * QSTR + sc8];
  };

  issue(0);
  for (int kv0 = 0; kv0 < kvend; kv0 += KVBLK) {
    __syncthreads();   // previous tile's LDS reads done
    // K rows (row-major, pad 136), two 64-row sub-buffers
    *(short8*)&Ks[0][srow * 136 + sc8] = kreg[0];
    *(short8*)&Ks[0][(srow + 32) * 136 + sc8] = kreg[1];
    *(short8*)&Ks[1][srow * 136 + sc8] = kreg[2];
    *(short8*)&Ks[1][(srow + 32) * 136 + sc8] = kreg[3];
    // V transposed as u32 kv-pairs, XOR-swizzled, two sub-buffers
#pragma unroll
    for (int e = 0; e < 8; ++e) {
      int d = sc8 + e;
      unsigned pk0 = (unsigned)(u16)vreg[0][e] | ((unsigned)(u16)vreg[1][e] << 16);
      unsigned pk1 = (unsigned)(u16)vreg[2][e] | ((unsigned)(u16)vreg[3][e] << 16);
      int byteoff = (d * 144 + 4 * srow) ^ (((d >> 3) & 7) << 4);
      *(unsigned*)((char*)&Vt32[0][0] + byteoff) = pk0;
      *(unsigned*)((char*)&Vt32[1][0] + byteoff) = pk1;
    }
    __syncthreads();   // staged tile visible
    if (kv0 + KVBLK < kvend) issue(kv0 + KVBLK);  // overlap next loads with compute

    attn_tile(qaA, oA, olA, mA, rowA, kv0,      &Ks[0][0], &Vt32[0][0], &Ps[wid][0], l15, lh, ones8);
    attn_tile(qaA, oA, olA, mA, rowA, kv0 + 64, &Ks[1][0], &Vt32[1][0], &Ps[wid][0], l15, lh, ones8);
    attn_tile(qaB, oB, olB, mB, rowB, kv0,      &Ks[0][0], &Vt32[0][0], &Ps[wid][0], l15, lh, ones8);
    attn_tile(qaB, oB, olB, mB, rowB, kv0 + 64, &Ks[1][0], &Vt32[1][0], &Ps[wid][0], l15, lh, ones8);
  }

  f32x4 invA, invB;
#pragma unroll
  for (int j = 0; j < 4; ++j) {
    invA[j] = __builtin_amdgcn_rcpf(olA[j]);
    invB[j] = __builtin_amdgcn_rcpf(olB[j]);
  }
#pragma unroll
  for (int nt = 0; nt < 8; ++nt)
#pragma unroll
    for (int j = 0; j < 4; ++j) {
      Y[(size_t)(b * TT + rowA + lh * 4 + j) * DD + h * HD + nt * 16 + l15] =
          f2b(oA[nt][j] * invA[j]);
      Y[(size_t)(b * TT + rowB + lh * 4 + j) * DD + h * HD + nt * 16 + l15] =
          f2b(oB[nt][j] * invB[j]);
    }
}

// ---------- launcher ----------
extern "C" void kernel_launch(void* const* d_in, const int* in_sizes, int n_in,
                              void* d_out, int out_size, void* d_ws, size_t ws_size,
                              hipStream_t stream) {
  const float* x    = (const float*)d_in[0];
  const float* rope = (const float*)d_in[1];
  const float* wq   = (const float*)d_in[2];
  const float* wk   = (const float*)d_in[3];
  const float* wv   = (const float*)d_in[4];
  const float* wo   = (const float*)d_in[5];
  float* out = (float*)d_out;

  char* ws = (char*)d_ws;
  u16* xb    = (u16*)ws; ws += (size_t)MM * DD * 2;        // 16.8 MB
  u16* wqkvb = (u16*)ws; ws += (size_t)QSTR * DD * 2;      // 12.6 MB (wq|wk|wv rows)
  u16* wob   = (u16*)ws; ws += (size_t)DD * DD * 2;        //  8.4 MB
  u16* QKVb  = (u16*)ws; ws += (size_t)MM * QSTR * 2;      // 25.2 MB
  u16* Yb    = (u16*)ws;                                   // 16.8 MB

  // 1) fused converts: x, wq, wk, wv, wo in ONE launch
  cvt_all<<<2048, 256, 0, stream>>>(x, wq, wk, wv, wo, xb, wqkvb, wob);

  // 2) fused QKV projection: one M=4096, N=3072, K=2048 GEMM
  gemm_bt<true><<<dim3(QSTR / 128, MM / 128), 256, 0, stream>>>(xb, wqkvb, QKVb, MM, QSTR, DD);

  // 3) fused RoPE (Q with softmax scale + K) in ONE launch
  rope_all<<<(ROPE_QN + MM * NKVH * 64) / 256, 256, 0, stream>>>(QKVb, rope);

  // 4) attention (R0 paired structure, KVBLK=128)
  attn_kernel<<<BB * NH * (TT / QBLK / 2), 512, 0, stream>>>(QKVb, Yb);

  // 5) output projection (fp32 out)
  gemm_bt<false><<<dim3(DD / 128, MM / 128), 256, 0, stream>>>(Yb, wob, out, MM, DD, DD);
}

// Round 7
// 226.567 us; speedup vs baseline: 1.2756x; 1.0277x over previous
//
#include <hip/hip_runtime.h>

// ---------- types & helpers ----------
typedef unsigned short u16;
typedef float   f32x4  __attribute__((ext_vector_type(4)));
typedef short   short8 __attribute__((ext_vector_type(8)));
typedef __bf16  bf16x8 __attribute__((ext_vector_type(8)));
typedef float   float4v __attribute__((ext_vector_type(4)));
typedef unsigned short u16x4 __attribute__((ext_vector_type(4)));

// native HW bf16 convert (RNE, v_cvt_pk_bf16_f32) — do not hand-roll (T12/m240)
static __device__ __forceinline__ u16 f2b(float f) {
  return __builtin_bit_cast(u16, (__bf16)f);
}
static __device__ __forceinline__ float b2f(u16 h) {
  union { unsigned u; float f; } v; v.u = ((unsigned)h) << 16;
  return v.f;
}
static __device__ __forceinline__ f32x4 mfma_bf16(short8 a, short8 b, f32x4 c) {
  return __builtin_amdgcn_mfma_f32_16x16x32_bf16(
      __builtin_bit_cast(bf16x8, a), __builtin_bit_cast(bf16x8, b), c, 0, 0, 0);
}
// async global->LDS, 16B per lane; lds ptr must be wave-uniform base (HW adds lane*16)
static __device__ __forceinline__ void gload_lds16(const u16* g, u16* l) {
  __builtin_amdgcn_global_load_lds(
      (const __attribute__((address_space(1))) unsigned int*)g,
      (__attribute__((address_space(3))) unsigned int*)l, 16, 0, 0);
}

// ---------- problem constants ----------
#define BB 2
#define TT 2048
#define DD 2048
#define NH 16
#define NKVH 4
#define HD 128
#define MM (BB * TT)          // 4096 rows
#define QSTR 3072             // fused QKV projection row: [Q(2048) | K(512) | V(512)]
#define QSCALE 0.08838834764831845f

// ---------- fused fp32 -> bf16 convert (all 5 tensors, 1 launch) ----------
#define N4_X   ((MM * DD) / 4)
#define N4_WQ  ((DD * DD) / 4)
#define N4_WKV ((NKVH * HD * DD) / 4)
#define N4_WO  ((DD * DD) / 4)
#define N4_TOT (N4_X + N4_WQ + 2 * N4_WKV + N4_WO)

__global__ __launch_bounds__(256) void cvt_all(const float* __restrict__ x,
                                               const float* __restrict__ wq,
                                               const float* __restrict__ wk,
                                               const float* __restrict__ wv,
                                               const float* __restrict__ wo,
                                               u16* __restrict__ xb,
                                               u16* __restrict__ wqkvb,
                                               u16* __restrict__ wob) {
  int stride = gridDim.x * blockDim.x;
  for (int i = blockIdx.x * blockDim.x + threadIdx.x; i < N4_TOT; i += stride) {
    const float4v* src;
    u16x4* dst;
    int off;
    if (i < N4_X) {
      src = (const float4v*)x; dst = (u16x4*)xb; off = i;
    } else if (i < N4_X + N4_WQ) {
      src = (const float4v*)wq; dst = (u16x4*)wqkvb; off = i - N4_X;
    } else if (i < N4_X + N4_WQ + N4_WKV) {
      src = (const float4v*)wk; dst = (u16x4*)wqkvb + N4_WQ; off = i - (N4_X + N4_WQ);
    } else if (i < N4_X + N4_WQ + 2 * N4_WKV) {
      src = (const float4v*)wv; dst = (u16x4*)wqkvb + N4_WQ + N4_WKV;
      off = i - (N4_X + N4_WQ + N4_WKV);
    } else {
      src = (const float4v*)wo; dst = (u16x4*)wob; off = i - (N4_X + N4_WQ + 2 * N4_WKV);
    }
    float4v v = src[off];
    u16x4 o;
    o[0] = f2b(v[0]); o[1] = f2b(v[1]); o[2] = f2b(v[2]); o[3] = f2b(v[3]);
    dst[off] = o;
  }
}

// ---------- RoPE on K only (Q-rope is fused into the attention prologue) ----------
__global__ __launch_bounds__(256) void rope_k(u16* __restrict__ K,
                                              const float* __restrict__ rope) {
  int idx = blockIdx.x * 256 + threadIdx.x;
  int i  = idx & 63;
  int h  = (idx >> 6) & (NKVH - 1);
  int bt = idx >> 8;
  int t  = bt & (TT - 1);
  size_t base = (size_t)bt * QSTR + h * HD + i;
  float x1 = b2f(K[base]);
  float x2 = b2f(K[base + 64]);
  float c = rope[t * 128 + 2 * i];
  float s = rope[t * 128 + 2 * i + 1];
  K[base]      = f2b(x1 * c - x2 * s);
  K[base + 64] = f2b(x1 * s + x2 * c);
}

// ---------- GEMM (m97 structure): C[M,N] = A[M,K] * W[N,K]^T ----------
// + T1 bijective XCD swizzle (both launches have nwg % 8 == 0).
template <bool OUTBF>
__global__ __launch_bounds__(256) void gemm_bt(const u16* __restrict__ A,
                                               const u16* __restrict__ W,
                                               void* __restrict__ Cout,
                                               int M, int N, int K) {
  __shared__ __align__(16) u16 As[128 * 32];
  __shared__ __align__(16) u16 Ws[128 * 32];
  const int tid = threadIdx.x, lane = tid & 63, wid = tid >> 6;
  const int wr = wid >> 1, wc = wid & 1;
  // XCD-aware remap: contiguous chunk of the linear grid per XCD (T1)
  const int gx = gridDim.x;
  const int lin = blockIdx.y * gx + blockIdx.x;
  const int cpx = (gx * gridDim.y) >> 3;
  const int swz = (lin & 7) * cpx + (lin >> 3);
  const int brow = (swz / gx) * 128, bcol = (swz % gx) * 128;
  const int l15 = lane & 15, lh = lane >> 4;

  const int c0 = wid * 64 + lane;
  const int c1 = c0 + 256;
  const u16* Ag0 = A + (size_t)(brow + (c0 >> 2)) * K + ((c0 & 3) << 3);
  const u16* Ag1 = A + (size_t)(brow + (c1 >> 2)) * K + ((c1 & 3) << 3);
  const u16* Wg0 = W + (size_t)(bcol + (c0 >> 2)) * K + ((c0 & 3) << 3);
  const u16* Wg1 = W + (size_t)(bcol + (c1 >> 2)) * K + ((c1 & 3) << 3);
  u16* lA0 = &As[(wid * 64) * 8];
  u16* lA1 = &As[(wid * 64 + 256) * 8];
  u16* lW0 = &Ws[(wid * 64) * 8];
  u16* lW1 = &Ws[(wid * 64 + 256) * 8];

  f32x4 acc[4][4];
#pragma unroll
  for (int m = 0; m < 4; ++m)
#pragma unroll
    for (int n = 0; n < 4; ++n) acc[m][n] = (f32x4)0.0f;

  for (int k0 = 0; k0 < K; k0 += 32) {
    __syncthreads();
    gload_lds16(Ag0 + k0, lA0);
    gload_lds16(Ag1 + k0, lA1);
    gload_lds16(Wg0 + k0, lW0);
    gload_lds16(Wg1 + k0, lW1);
    __syncthreads();
    short8 af[4], bfr[4];
#pragma unroll
    for (int m = 0; m < 4; ++m)
      af[m] = *(const short8*)&As[(wr * 64 + m * 16 + l15) * 32 + (lh << 3)];
#pragma unroll
    for (int n = 0; n < 4; ++n)
      bfr[n] = *(const short8*)&Ws[(wc * 64 + n * 16 + l15) * 32 + (lh << 3)];
#pragma unroll
    for (int m = 0; m < 4; ++m)
#pragma unroll
      for (int n = 0; n < 4; ++n)
        acc[m][n] = mfma_bf16(af[m], bfr[n], acc[m][n]);
  }

#pragma unroll
  for (int m = 0; m < 4; ++m)
#pragma unroll
    for (int n = 0; n < 4; ++n)
#pragma unroll
      for (int j = 0; j < 4; ++j) {
        int row = brow + wr * 64 + m * 16 + lh * 4 + j;
        int col = bcol + wc * 64 + n * 16 + l15;
        if (OUTBF)
          ((u16*)Cout)[(size_t)row * N + col] = f2b(acc[m][n][j]);
        else
          ((float*)Cout)[(size_t)row * N + col] = acc[m][n][j];
      }
}

// ---------- fused causal GQA flash attention ----------
// R6 structure (best measured): 256 blocks x 8 waves, paired q-tiles
// (qb, 15-qb), per-wave 16-row attn_tile, T14 staging, KVBLK=128 (two
// 64-row sub-buffers per barrier pair). New: Q-rope+scale fused into the
// prologue (pair (i,i+64) lives in qa[kk] / qa[kk^2] of the SAME lane).
#define QBLK 128
#define KVBLK 128

static __device__ __forceinline__ void attn_tile(
    const short8* qa, f32x4* o, f32x4& ol, float* mrow,
    int qrow0, int kv0,
    const u16* Ks, const unsigned* Vt32, u16* myP,
    int l15, int lh, short8 ones8) {
  if (kv0 > qrow0 + 15) return;   // fully masked for this wave

  f32x4 s[4];
#pragma unroll
  for (int nt = 0; nt < 4; ++nt) s[nt] = (f32x4)0.0f;
  __builtin_amdgcn_s_setprio(1);
#pragma unroll
  for (int nt = 0; nt < 4; ++nt)
#pragma unroll
    for (int kk = 0; kk < 4; ++kk) {
      short8 kb = *(const short8*)&Ks[(nt * 16 + l15) * 136 + kk * 32 + (lh << 3)];
      s[nt] = mfma_bf16(qa[kk], kb, s[nt]);
    }
  __builtin_amdgcn_s_setprio(0);

  const int qg = qrow0 + lh * 4;
#pragma unroll
  for (int j = 0; j < 4; ++j)
#pragma unroll
    for (int nt = 0; nt < 4; ++nt)
      if (kv0 + nt * 16 + l15 > qg + j) s[nt][j] = -1e30f;

  float mt[4];
#pragma unroll
  for (int j = 0; j < 4; ++j)
    mt[j] = fmaxf(fmaxf(s[0][j], s[1][j]), fmaxf(s[2][j], s[3][j]));
#pragma unroll
  for (int d = 1; d <= 8; d <<= 1)
#pragma unroll
    for (int j = 0; j < 4; ++j) mt[j] = fmaxf(mt[j], __shfl_xor(mt[j], d));

  // defer-max (T13): rescale only when max grew by > 8
  float gmax = mt[0] - mrow[0];
#pragma unroll
  for (int j = 1; j < 4; ++j) gmax = fmaxf(gmax, mt[j] - mrow[j]);
  if (!__all(gmax <= 8.0f)) {
#pragma unroll
    for (int j = 0; j < 4; ++j) {
      float mn = fmaxf(mrow[j], mt[j]);
      float a = __expf(mrow[j] - mn);
      mrow[j] = mn;
      ol[j] *= a;
#pragma unroll
      for (int n = 0; n < 8; ++n) o[n][j] *= a;
    }
  }

  f32x4 p[4];
#pragma unroll
  for (int nt = 0; nt < 4; ++nt)
#pragma unroll
    for (int j = 0; j < 4; ++j) p[nt][j] = __expf(s[nt][j] - mrow[j]);

  // P -> per-wave LDS (transpose to A-frag layout)
#pragma unroll
  for (int nt = 0; nt < 4; ++nt)
#pragma unroll
    for (int j = 0; j < 4; ++j)
      myP[(lh * 4 + j) * 72 + nt * 16 + l15] = f2b(p[nt][j]);

  // PV (+ row-sum via ones-MFMA instead of shuffles)
  __builtin_amdgcn_s_setprio(1);
#pragma unroll
  for (int c = 0; c < 2; ++c) {
    short8 pa = *(const short8*)&myP[l15 * 72 + c * 32 + (lh << 3)];
    ol = mfma_bf16(pa, ones8, ol);
#pragma unroll
    for (int nt2 = 0; nt2 < 8; ++nt2) {
      int d = nt2 * 16 + l15;
      int byteoff = (d * 144 + (c * 32 + lh * 8) * 2) ^ (((d >> 3) & 7) << 4);
      short8 vb = *(const short8*)((const char*)Vt32 + byteoff);
      o[nt2] = mfma_bf16(pa, vb, o[nt2]);
    }
  }
  __builtin_amdgcn_s_setprio(0);
}

__global__ __launch_bounds__(512) void attn_kernel(const u16* __restrict__ QKV,
                                                   const float* __restrict__ rope,
                                                   u16* __restrict__ Y) {
  __shared__ __align__(16) u16 Ks[2][64 * 136];        // 2 x 17408 B
  __shared__ __align__(16) unsigned Vt32[2][128 * 36]; // 2 x 18432 B
  __shared__ __align__(16) u16 Ps[8][16 * 72];         // 18432 B

  const int tid = threadIdx.x, lane = tid & 63, wid = tid >> 6;
  const int l15 = lane & 15, lh = lane >> 4;
  const int bid = blockIdx.x;
  const int qpair = bid & 7;
  const int h = (bid >> 3) & 15;
  const int b = bid >> 7;
  const int kvh = h >> 2;
  const int qtA = qpair, qtB = 15 - qpair;
  const int rowA = qtA * QBLK + wid * 16;
  const int rowB = qtB * QBLK + wid * 16;

  const u16* Kb_ = QKV + (size_t)b * TT * QSTR + DD + kvh * HD;  // K cols
  const u16* Vb_ = Kb_ + NKVH * HD;                              // V cols

  short8 ones8;
#pragma unroll
  for (int e = 0; e < 8; ++e) ones8[e] = (short)0x3F80;  // bf16 1.0

  short8 qaA[4], qaB[4];
  {
    const u16* qA = QKV + (size_t)(b * TT + rowA + l15) * QSTR + h * HD + (lh << 3);
    const u16* qB = QKV + (size_t)(b * TT + rowB + l15) * QSTR + h * HD + (lh << 3);
#pragma unroll
    for (int kk = 0; kk < 4; ++kk) {
      qaA[kk] = *(const short8*)(qA + kk * 32);
      qaB[kk] = *(const short8*)(qB + kk * 32);
    }
  }
  // ---- fused Q-RoPE + softmax scale (pair (i, i+64) = qa[kk] / qa[kk+2],
  // same lane, same element e; i = kk*32 + lh*8 + e, t = row + l15)
  {
    const float* rpA = rope + (size_t)(rowA + l15) * 128;
    const float* rpB = rope + (size_t)(rowB + l15) * 128;
#pragma unroll
    for (int kk = 0; kk < 2; ++kk)
#pragma unroll
      for (int e = 0; e < 8; ++e) {
        const int i2 = 2 * (kk * 32 + (lh << 3) + e);
        float c = rpA[i2], s = rpA[i2 + 1];
        float x1 = b2f((u16)qaA[kk][e]), x2 = b2f((u16)qaA[kk + 2][e]);
        qaA[kk][e]     = (short)f2b(QSCALE * (x1 * c - x2 * s));
        qaA[kk + 2][e] = (short)f2b(QSCALE * (x1 * s + x2 * c));
        float cb = rpB[i2], sb = rpB[i2 + 1];
        float y1 = b2f((u16)qaB[kk][e]), y2 = b2f((u16)qaB[kk + 2][e]);
        qaB[kk][e]     = (short)f2b(QSCALE * (y1 * cb - y2 * sb));
        qaB[kk + 2][e] = (short)f2b(QSCALE * (y1 * sb + y2 * cb));
      }
  }

  f32x4 oA[8], oB[8];
  f32x4 olA = (f32x4)0.0f, olB = (f32x4)0.0f;
  float mA[4], mB[4];
#pragma unroll
  for (int n = 0; n < 8; ++n) { oA[n] = (f32x4)0.0f; oB[n] = (f32x4)0.0f; }
#pragma unroll
  for (int j = 0; j < 4; ++j) { mA[j] = -1e30f; mB[j] = -1e30f; }

  const int kvend = (qtB + 1) * QBLK;   // multiple of 128

  // staging registers (T14: issue early, write late); 128 KV rows per pass
  short8 kreg[4], vreg[4];
  const int srow = tid >> 4;           // 0..31
  const int sc8 = (tid & 15) << 3;

  auto issue = [&](int kv0) {
    kreg[0] = *(const short8*)&Kb_[(size_t)(kv0 + srow) * QSTR + sc8];
    kreg[1] = *(const short8*)&Kb_[(size_t)(kv0 + 32 + srow) * QSTR + sc8];
    kreg[2] = *(const short8*)&Kb_[(size_t)(kv0 + 64 + srow) * QSTR + sc8];
    kreg[3] = *(const short8*)&Kb_[(size_t)(kv0 + 96 + srow) * QSTR + sc8];
    vreg[0] = *(const short8*)&Vb_[(size_t)(kv0 + 2 * srow) * QSTR + sc8];
    vreg[1] = *(const short8*)&Vb_[(size_t)(kv0 + 2 * srow + 1) * QSTR + sc8];
    vreg[2] = *(const short8*)&Vb_[(size_t)(kv0 + 64 + 2 * srow) * QSTR + sc8];
    vreg[3] = *(const short8*)&Vb_[(size_t)(kv0 + 64 + 2 * srow + 1) * QSTR + sc8];
  };

  issue(0);
  for (int kv0 = 0; kv0 < kvend; kv0 += KVBLK) {
    __syncthreads();   // previous tile's LDS reads done
    // K rows (row-major, pad 136), two 64-row sub-buffers
    *(short8*)&Ks[0][srow * 136 + sc8] = kreg[0];
    *(short8*)&Ks[0][(srow + 32) * 136 + sc8] = kreg[1];
    *(short8*)&Ks[1][srow * 136 + sc8] = kreg[2];
    *(short8*)&Ks[1][(srow + 32) * 136 + sc8] = kreg[3];
    // V transposed as u32 kv-pairs, XOR-swizzled, two sub-buffers
#pragma unroll
    for (int e = 0; e < 8; ++e) {
      int d = sc8 + e;
      unsigned pk0 = (unsigned)(u16)vreg[0][e] | ((unsigned)(u16)vreg[1][e] << 16);
      unsigned pk1 = (unsigned)(u16)vreg[2][e] | ((unsigned)(u16)vreg[3][e] << 16);
      int byteoff = (d * 144 + 4 * srow) ^ (((d >> 3) & 7) << 4);
      *(unsigned*)((char*)&Vt32[0][0] + byteoff) = pk0;
      *(unsigned*)((char*)&Vt32[1][0] + byteoff) = pk1;
    }
    __syncthreads();   // staged tile visible
    if (kv0 + KVBLK < kvend) issue(kv0 + KVBLK);  // overlap next loads with compute

    attn_tile(qaA, oA, olA, mA, rowA, kv0,      &Ks[0][0], &Vt32[0][0], &Ps[wid][0], l15, lh, ones8);
    attn_tile(qaA, oA, olA, mA, rowA, kv0 + 64, &Ks[1][0], &Vt32[1][0], &Ps[wid][0], l15, lh, ones8);
    attn_tile(qaB, oB, olB, mB, rowB, kv0,      &Ks[0][0], &Vt32[0][0], &Ps[wid][0], l15, lh, ones8);
    attn_tile(qaB, oB, olB, mB, rowB, kv0 + 64, &Ks[1][0], &Vt32[1][0], &Ps[wid][0], l15, lh, ones8);
  }

  f32x4 invA, invB;
#pragma unroll
  for (int j = 0; j < 4; ++j) {
    invA[j] = __builtin_amdgcn_rcpf(olA[j]);
    invB[j] = __builtin_amdgcn_rcpf(olB[j]);
  }
#pragma unroll
  for (int nt = 0; nt < 8; ++nt)
#pragma unroll
    for (int j = 0; j < 4; ++j) {
      Y[(size_t)(b * TT + rowA + lh * 4 + j) * DD + h * HD + nt * 16 + l15] =
          f2b(oA[nt][j] * invA[j]);
      Y[(size_t)(b * TT + rowB + lh * 4 + j) * DD + h * HD + nt * 16 + l15] =
          f2b(oB[nt][j] * invB[j]);
    }
}

// ---------- launcher ----------
extern "C" void kernel_launch(void* const* d_in, const int* in_sizes, int n_in,
                              void* d_out, int out_size, void* d_ws, size_t ws_size,
                              hipStream_t stream) {
  const float* x    = (const float*)d_in[0];
  const float* rope = (const float*)d_in[1];
  const float* wq   = (const float*)d_in[2];
  const float* wk   = (const float*)d_in[3];
  const float* wv   = (const float*)d_in[4];
  const float* wo   = (const float*)d_in[5];
  float* out = (float*)d_out;

  char* ws = (char*)d_ws;
  u16* xb    = (u16*)ws; ws += (size_t)MM * DD * 2;        // 16.8 MB
  u16* wqkvb = (u16*)ws; ws += (size_t)QSTR * DD * 2;      // 12.6 MB (wq|wk|wv rows)
  u16* wob   = (u16*)ws; ws += (size_t)DD * DD * 2;        //  8.4 MB
  u16* QKVb  = (u16*)ws; ws += (size_t)MM * QSTR * 2;      // 25.2 MB
  u16* Yb    = (u16*)ws;                                   // 16.8 MB

  // 1) fused converts: x, wq, wk, wv, wo in ONE launch
  cvt_all<<<2048, 256, 0, stream>>>(x, wq, wk, wv, wo, xb, wqkvb, wob);

  // 2) fused QKV projection: one M=4096, N=3072, K=2048 GEMM (T1 swizzled)
  gemm_bt<true><<<dim3(QSTR / 128, MM / 128), 256, 0, stream>>>(xb, wqkvb, QKVb, MM, QSTR, DD);

  // 3) RoPE on K only (Q-rope fused into attention)
  rope_k<<<(MM * NKVH * 64) / 256, 256, 0, stream>>>(QKVb + DD, rope);

  // 4) attention (R6 structure + fused Q-rope)
  attn_kernel<<<BB * NH * (TT / QBLK / 2), 512, 0, stream>>>(QKVb, rope, Yb);

  // 5) output projection (fp32 out, T1 swizzled)
  gemm_bt<false><<<dim3(DD / 128, MM / 128), 256, 0, stream>>>(Yb, wob, out, MM, DD, DD);
}